// Round 16
// baseline (191.807 us; speedup 1.0000x reference)
//
#include <hip/hip_runtime.h>

// MeanGraphSage: h = relu(concat(x @ Ws, mean_neighbors @ Wn) + bias)
// N=50000 nodes, E=800000 edges, D=64 in-feats, 128 out (64+64 concat).
//
// Round 16: r15 deadlocked from a barrier-target bug (separate counters but
// cumulative targets NB/2NB/3NB -- bar+1 could never reach 2*NB). Fixed:
// every gridbar waits for NB arrivals on ITS OWN counter. Structure
// otherwise identical to r15:
//   prep (x->bf16 + zero bar) ->
//   csr_build (hist -> grid-bar -> column scan -> grid-bar -> boffs ->
//              reg-staged scatter -> grid-bar -> node sort) ->
//   sage_aggregate (r14 dwordx4) -> sage_project (r13 MFMA).
// 196 blocks x 4 waves, ~4.4KB LDS -> co-residency on 256 CUs guaranteed.

typedef unsigned long long ull;
typedef __attribute__((ext_vector_type(8))) short bf16x8;
typedef __attribute__((ext_vector_type(4))) float f32x4;

constexpr int N_NODES = 50000;
constexpr int N_EDGES = 800000;
constexpr int D = 64;
constexpr int UNITS = 128;
constexpr int NB = (N_NODES + 255) / 256;           // 196 buckets of 256 nodes
constexpr int SC_EPT = 16;                           // edges/thread
constexpr int SC_THREADS = 256;
constexpr int SC_CHUNK = SC_EPT * SC_THREADS;        // 4096
constexpr int SC_BLOCKS = (N_EDGES + SC_CHUNK - 1) / SC_CHUNK;  // 196 (== NB)
constexpr int NS_EPT = 24;                           // bucket capacity 6144
constexpr int PREP_BLOCKS = 2048;
constexpr int NTILES = N_NODES / 16;                 // 3125
constexpr int PJ_BLOCKS = (NTILES + 3) / 4;          // 782

__device__ __forceinline__ unsigned f2bf(float f) {   // RNE f32 -> bf16 bits
    unsigned u = __float_as_uint(f);
    return (u + 0x7fffu + ((u >> 16) & 1u)) >> 16;
}
__device__ __forceinline__ float bf2f(unsigned b) {
    return __uint_as_float(b << 16);
}

// Software grid barrier: each barrier has its OWN counter; target = #blocks.
// Counters pre-zeroed by the preceding dispatch (prep).
__device__ __forceinline__ void gridbar(int* ctr, int target) {
    __threadfence();                 // flush my writes device-wide
    __syncthreads();
    if (threadIdx.x == 0) {
        __hip_atomic_fetch_add(ctr, 1, __ATOMIC_RELEASE, __HIP_MEMORY_SCOPE_AGENT);
        while (__hip_atomic_load(ctr, __ATOMIC_ACQUIRE, __HIP_MEMORY_SCOPE_AGENT) < target) {
            __builtin_amdgcn_s_sleep(8);
        }
    }
    __syncthreads();
    __threadfence();                 // no stale reads after the barrier
}

// ---------------- prep: x->bf16 table + zero barrier counters ----------------
__global__ __launch_bounds__(256) void prep(const float* __restrict__ x,
                                            unsigned* __restrict__ xh,
                                            int* __restrict__ bar) {
    if (blockIdx.x == 0 && threadIdx.x < 8) bar[threadIdx.x] = 0;
    constexpr int XW = N_NODES * (D / 2);   // 1.6M packed words
    for (int i = blockIdx.x * 256 + threadIdx.x; i < XW; i += PREP_BLOCKS * 256) {
        const float2 v = ((const float2*)x)[i];
        xh[i] = f2bf(v.x) | (f2bf(v.y) << 16);
    }
}

// ---------------- fused CSR build: hist -> scan -> scatter -> node sort -----
__global__ __launch_bounds__(256) void csr_build(const int* __restrict__ ei,
                                                 const float* __restrict__ ew,
                                                 int* __restrict__ partial,
                                                 int* __restrict__ btot,
                                                 int* __restrict__ bar,
                                                 int* __restrict__ offs,
                                                 ull* __restrict__ packed,
                                                 unsigned* __restrict__ cedges) {
    __shared__ int lh[NB];        // hist, later per-bucket cursor
    __shared__ int lbase[NB];
    __shared__ int sb[256];       // scan scratch
    __shared__ int bofs[NB + 1];
    __shared__ int cur[256];
    const int b = blockIdx.x;
    const int t = threadIdx.x;

    // ---- phase 1: stage chunk in registers + bucket histogram
    int   rows[SC_EPT];
    int   cols[SC_EPT];
    float wts[SC_EPT];
    for (int i = t; i < NB; i += 256) lh[i] = 0;
    __syncthreads();
    const int e0 = b * SC_CHUNK + t;
    #pragma unroll
    for (int i = 0; i < SC_EPT; ++i) {
        const int e = e0 + i * SC_THREADS;
        if (e < N_EDGES) {
            rows[i] = ei[e];
            cols[i] = ei[N_EDGES + e];
            wts[i]  = ew[e];
            atomicAdd(&lh[rows[i] >> 8], 1);
        } else {
            rows[i] = -1;
        }
    }
    __syncthreads();
    for (int i = t; i < NB; i += 256) partial[(size_t)b * NB + i] = lh[i];
    gridbar(bar + 0, NB);

    // ---- phase 2: column scan (block b owns bucket/column b)
    {
        const int v = (t < SC_BLOCKS) ? partial[(size_t)t * NB + b] : 0;
        sb[t] = v;
        __syncthreads();
        for (int d2 = 1; d2 < 256; d2 <<= 1) {
            int u = (t >= d2) ? sb[t - d2] : 0;
            __syncthreads();
            sb[t] += u;
            __syncthreads();
        }
        if (t < SC_BLOCKS) partial[(size_t)t * NB + b] = sb[t] - v;
        if (t == 255) btot[b] = sb[255];
    }
    gridbar(bar + 1, NB);

    // ---- phase 2b: bucket offsets (bofs) in LDS; per-block bases (lbase)
    {
        const int bv = (t < NB) ? btot[t] : 0;
        sb[t] = bv;
        __syncthreads();
        for (int d2 = 1; d2 < 256; d2 <<= 1) {
            int u = (t >= d2) ? sb[t - d2] : 0;
            __syncthreads();
            sb[t] += u;
            __syncthreads();
        }
        if (t < NB) bofs[t] = sb[t] - bv;
        if (t == 255) bofs[NB] = sb[255];
        __syncthreads();
        for (int i = t; i < NB; i += 256) {
            lbase[i] = bofs[i] + partial[(size_t)b * NB + i];
            lh[i]    = 0;   // reuse as per-bucket cursor
        }
    }
    __syncthreads();

    // ---- phase 3: scatter from registers into bucket runs
    #pragma unroll
    for (int i = 0; i < SC_EPT; ++i) {
        if (rows[i] >= 0) {
            const int bb   = rows[i] >> 8;
            const int lpos = atomicAdd(&lh[bb], 1);
            const unsigned hi = (unsigned)cols[i] | ((unsigned)(rows[i] & 255) << 16);
            packed[lbase[bb] + lpos] = ((ull)hi << 32) | (ull)(unsigned)__float_as_uint(wts[i]);
        }
    }
    gridbar(bar + 2, NB);

    // ---- phase 4: within-bucket node sort + CSR offsets + 4B compaction
    {
        const int s = bofs[b];
        const int e = bofs[b + 1];
        ull st[NS_EPT];
        #pragma unroll
        for (int i = 0; i < NS_EPT; ++i) {
            const int idx = s + t + i * 256;
            st[i] = (idx < e) ? packed[idx] : ~0ull;
        }
        cur[t] = 0;
        __syncthreads();
        #pragma unroll
        for (int i = 0; i < NS_EPT; ++i) {
            if (st[i] != ~0ull) atomicAdd(&cur[(int)((st[i] >> 48) & 0xff)], 1);
        }
        __syncthreads();
        const int v = cur[t];
        sb[t] = v;
        __syncthreads();
        for (int d2 = 1; d2 < 256; d2 <<= 1) {
            int u = (t >= d2) ? sb[t - d2] : 0;
            __syncthreads();
            sb[t] += u;
            __syncthreads();
        }
        const int excl = sb[t] - v;
        const int n = b * 256 + t;
        if (n < N_NODES) offs[n] = s + excl;
        if (b == 0 && t == 0) offs[N_NODES] = N_EDGES;
        cur[t] = excl;
        __syncthreads();
        #pragma unroll
        for (int i = 0; i < NS_EPT; ++i) {
            if (st[i] != ~0ull) {
                const int r8  = (int)((st[i] >> 48) & 0xff);
                const int pos = atomicAdd(&cur[r8], 1);
                const unsigned hi  = (unsigned)(st[i] >> 32);
                const unsigned col = hi & 0xffffu;
                const unsigned wbf = f2bf(__uint_as_float((unsigned)st[i]));
                cedges[s + pos] = (col << 16) | wbf;
            }
        }
    }
}

// ---------------- half-wave-per-node aggregation (dwordx4 gathers) --------
__global__ __launch_bounds__(256) void sage_aggregate(const unsigned* __restrict__ xh,
                                                      const int* __restrict__ offs,
                                                      const unsigned* __restrict__ cedges,
                                                      unsigned* __restrict__ meanh) {
    const int n = (blockIdx.x * 256 + threadIdx.x) >> 5;   // half-wave id = node
    if (n >= N_NODES) return;
    const int l32 = threadIdx.x & 31;
    const int eg  = l32 >> 3;
    const int wq  = l32 & 7;
    const int s = offs[n];
    const int t = offs[n + 1];

    float ax0 = 0.f, ay0 = 0.f, ax1 = 0.f, ay1 = 0.f;
    float ax2 = 0.f, ay2 = 0.f, ax3 = 0.f, ay3 = 0.f;
    float bx0 = 0.f, by0 = 0.f, bx1 = 0.f, by1 = 0.f;
    float bx2 = 0.f, by2 = 0.f, bx3 = 0.f, by3 = 0.f;

    if (t > s) {
        const int tm1 = t - 1;
        for (int g = s; g < t; g += 8) {
            const int eA = g + eg;
            const int eB = g + 4 + eg;
            const unsigned cA = cedges[min(eA, tm1)];
            const unsigned cB = cedges[min(eB, tm1)];
            const float wA = (eA < t) ? bf2f(cA & 0xffffu) : 0.0f;
            const float wB = (eB < t) ? bf2f(cB & 0xffffu) : 0.0f;
            const uint4 vA = *(const uint4*)(xh + (size_t)(cA >> 16) * (D / 2) + wq * 4);
            const uint4 vB = *(const uint4*)(xh + (size_t)(cB >> 16) * (D / 2) + wq * 4);
            ax0 = fmaf(__uint_as_float(vA.x << 16),         wA, ax0);
            ay0 = fmaf(__uint_as_float(vA.x & 0xffff0000u), wA, ay0);
            ax1 = fmaf(__uint_as_float(vA.y << 16),         wA, ax1);
            ay1 = fmaf(__uint_as_float(vA.y & 0xffff0000u), wA, ay1);
            ax2 = fmaf(__uint_as_float(vA.z << 16),         wA, ax2);
            ay2 = fmaf(__uint_as_float(vA.z & 0xffff0000u), wA, ay2);
            ax3 = fmaf(__uint_as_float(vA.w << 16),         wA, ax3);
            ay3 = fmaf(__uint_as_float(vA.w & 0xffff0000u), wA, ay3);
            bx0 = fmaf(__uint_as_float(vB.x << 16),         wB, bx0);
            by0 = fmaf(__uint_as_float(vB.x & 0xffff0000u), wB, by0);
            bx1 = fmaf(__uint_as_float(vB.y << 16),         wB, bx1);
            by1 = fmaf(__uint_as_float(vB.y & 0xffff0000u), wB, by1);
            bx2 = fmaf(__uint_as_float(vB.z << 16),         wB, bx2);
            by2 = fmaf(__uint_as_float(vB.z & 0xffff0000u), wB, by2);
            bx3 = fmaf(__uint_as_float(vB.w << 16),         wB, bx3);
            by3 = fmaf(__uint_as_float(vB.w & 0xffff0000u), wB, by3);
        }
    }
    float sx0 = ax0 + bx0, sy0 = ay0 + by0;
    float sx1 = ax1 + bx1, sy1 = ay1 + by1;
    float sx2 = ax2 + bx2, sy2 = ay2 + by2;
    float sx3 = ax3 + bx3, sy3 = ay3 + by3;
    sx0 += __shfl_xor(sx0, 8);  sx0 += __shfl_xor(sx0, 16);
    sy0 += __shfl_xor(sy0, 8);  sy0 += __shfl_xor(sy0, 16);
    sx1 += __shfl_xor(sx1, 8);  sx1 += __shfl_xor(sx1, 16);
    sy1 += __shfl_xor(sy1, 8);  sy1 += __shfl_xor(sy1, 16);
    sx2 += __shfl_xor(sx2, 8);  sx2 += __shfl_xor(sx2, 16);
    sy2 += __shfl_xor(sy2, 8);  sy2 += __shfl_xor(sy2, 16);
    sx3 += __shfl_xor(sx3, 8);  sx3 += __shfl_xor(sx3, 16);
    sy3 += __shfl_xor(sy3, 8);  sy3 += __shfl_xor(sy3, 16);

    if (eg == 0) {
        const float inv = 1.0f / fmaxf((float)(t - s), 1.0f);
        uint4 r;
        r.x = f2bf(sx0 * inv) | (f2bf(sy0 * inv) << 16);
        r.y = f2bf(sx1 * inv) | (f2bf(sy1 * inv) << 16);
        r.z = f2bf(sx2 * inv) | (f2bf(sy2 * inv) << 16);
        r.w = f2bf(sx3 * inv) | (f2bf(sy3 * inv) << 16);
        *(uint4*)(meanh + (size_t)n * (D / 2) + wq * 4) = r;
    }
}

// ---------------- MFMA projection: 16-node x 128-output tile per wave -----
__global__ __launch_bounds__(256) void sage_project(const unsigned* __restrict__ xh,
                                                    const unsigned* __restrict__ meanh,
                                                    const float* __restrict__ skern,
                                                    const float* __restrict__ nkern,
                                                    const float* __restrict__ bias,
                                                    float* __restrict__ out) {
    const int lane = threadIdx.x & 63;
    const int wid  = (blockIdx.x * 256 + threadIdx.x) >> 6;
    const int r16  = lane & 15;
    const int g    = lane >> 4;

    bf16x8 bfrag[16];
    #pragma unroll
    for (int ct = 0; ct < 8; ++ct) {
        const float* K = (ct < 4) ? skern : nkern;
        const int col = (ct & 3) * 16 + r16;
        #pragma unroll
        for (int kh = 0; kh < 2; ++kh) {
            bf16x8 f;
            #pragma unroll
            for (int j = 0; j < 8; ++j) {
                const int k = kh * 32 + 8 * g + j;
                f[j] = (short)f2bf(K[k * 64 + col]);
            }
            bfrag[ct * 2 + kh] = f;
        }
    }

    if (wid >= NTILES) return;
    const int n0 = wid * 16;

    const unsigned* xrow = xh    + (size_t)(n0 + r16) * (D / 2);
    const unsigned* mrow = meanh + (size_t)(n0 + r16) * (D / 2);
    const bf16x8 aS0 = *(const bf16x8*)(xrow + 4 * g);
    const bf16x8 aS1 = *(const bf16x8*)(xrow + 16 + 4 * g);
    const bf16x8 aN0 = *(const bf16x8*)(mrow + 4 * g);
    const bf16x8 aN1 = *(const bf16x8*)(mrow + 16 + 4 * g);

    f32x4 acc[8];
    #pragma unroll
    for (int ct = 0; ct < 8; ++ct) {
        f32x4 c = {0.f, 0.f, 0.f, 0.f};
        c = __builtin_amdgcn_mfma_f32_16x16x32_bf16(ct < 4 ? aS0 : aN0, bfrag[ct * 2 + 0], c, 0, 0, 0);
        c = __builtin_amdgcn_mfma_f32_16x16x32_bf16(ct < 4 ? aS1 : aN1, bfrag[ct * 2 + 1], c, 0, 0, 0);
        acc[ct] = c;
    }

    #pragma unroll
    for (int ct = 0; ct < 8; ++ct) {
        const int col = (ct < 4 ? 0 : 64) + (ct & 3) * 16 + r16;
        const float bj = bias[col];
        #pragma unroll
        for (int r = 0; r < 4; ++r) {
            const int node = n0 + 4 * g + r;
            out[(size_t)node * UNITS + col] = fmaxf(acc[ct][r] + bj, 0.0f);
        }
    }
}

extern "C" void kernel_launch(void* const* d_in, const int* in_sizes, int n_in,
                              void* d_out, int out_size, void* d_ws, size_t ws_size,
                              hipStream_t stream) {
    const float* x     = (const float*)d_in[0];
    const int*   ei    = (const int*)  d_in[1];
    const float* ew    = (const float*)d_in[2];
    const float* skern = (const float*)d_in[3];
    const float* nkern = (const float*)d_in[4];
    const float* bias  = (const float*)d_in[5];
    float* out = (float*)d_out;

    auto align256 = [](size_t v) { return (v + 255) & ~size_t(255); };
    const size_t szM  = align256((size_t)SC_BLOCKS * NB * sizeof(int));   // partials matrix
    const size_t szT  = align256((size_t)NB * sizeof(int));               // bucket totals
    const size_t szB  = align256(8 * sizeof(int));                        // barrier counters
    const size_t szNO = align256((size_t)(N_NODES + 1) * sizeof(int));
    const size_t szP  = align256((size_t)N_EDGES * sizeof(ull));
    const size_t szC  = align256((size_t)N_EDGES * sizeof(unsigned));
    const size_t szX  = align256((size_t)N_NODES * (D / 2) * sizeof(unsigned));

    char* w = (char*)d_ws;
    int*      partial = (int*)w;
    int*      btot    = (int*)(w + szM);
    int*      bar     = (int*)(w + szM + szT);
    int*      offs    = (int*)(w + szM + szT + szB);
    ull*      packed  = (ull*)(w + szM + szT + szB + szNO);
    unsigned* cedges  = (unsigned*)(w + szM + szT + szB + szNO + szP);
    unsigned* xh      = (unsigned*)(w + szM + szT + szB + szNO + szP + szC);
    unsigned* meanh   = (unsigned*)(w + szM + szT + szB + szNO + szP + szC + szX);
    (void)ws_size; (void)in_sizes; (void)n_in; (void)out_size;

    prep          <<<PREP_BLOCKS, 256, 0, stream>>>(x, xh, bar);
    csr_build     <<<NB, 256, 0, stream>>>(ei, ew, partial, btot, bar, offs, packed, cedges);
    sage_aggregate<<<(N_NODES * 32 + 255) / 256, 256, 0, stream>>>(xh, offs, cedges, meanh);
    sage_project  <<<PJ_BLOCKS, 256, 0, stream>>>(xh, meanh, skern, nkern, bias, out);
}

// Round 17
// 60.519 us; speedup vs baseline: 3.1694x; 3.1694x over previous
//
#include <hip/hip_runtime.h>

// MeanGraphSage: h = relu(concat(x @ Ws, mean_neighbors @ Wn) + bias)
// N=50000 nodes, E=800000 edges, D=64 in-feats, 128 out (64+64 concat).
//
// Round 17: revert r16's fused csr_build (VGPR spill -> scratch, 160us).
// Back to r14 (64.7us) + int4/float4 edge-stream loads in prep-hist and
// edge_scatter (48+16 scalar dword loads/thread -> 12+4 dwordx4).

typedef unsigned long long ull;
typedef __attribute__((ext_vector_type(8))) short bf16x8;
typedef __attribute__((ext_vector_type(4))) float f32x4;

constexpr int N_NODES = 50000;
constexpr int N_EDGES = 800000;
constexpr int D = 64;
constexpr int UNITS = 128;
constexpr int NB = (N_NODES + 255) / 256;           // 196 buckets of 256 nodes
constexpr int SC_EPT = 16;                           // edges/thread
constexpr int SC_THREADS = 256;
constexpr int SC_CHUNK = SC_EPT * SC_THREADS;        // 4096
constexpr int SC_BLOCKS = (N_EDGES + SC_CHUNK - 1) / SC_CHUNK;  // 196
constexpr int NS_EPT = 24;                           // bucket capacity 6144
constexpr int PREP_BLOCKS = 2048;
constexpr int NTILES = N_NODES / 16;                 // 3125
constexpr int PJ_BLOCKS = (NTILES + 3) / 4;          // 782

__device__ __forceinline__ unsigned f2bf(float f) {   // RNE f32 -> bf16 bits
    unsigned u = __float_as_uint(f);
    return (u + 0x7fffu + ((u >> 16) & 1u)) >> 16;
}
__device__ __forceinline__ float bf2f(unsigned b) {
    return __uint_as_float(b << 16);
}

// ---------------- prep: x->bf16 table + bucket histogram (int4 loads) -------
__global__ __launch_bounds__(256) void prep(const float* __restrict__ x,
                                            unsigned* __restrict__ xh,
                                            const int* __restrict__ ei,
                                            int* __restrict__ partial) {
    constexpr int XW = N_NODES * (D / 2);   // 1.6M packed words
    for (int i = blockIdx.x * 256 + threadIdx.x; i < XW; i += PREP_BLOCKS * 256) {
        const float2 v = ((const float2*)x)[i];
        xh[i] = f2bf(v.x) | (f2bf(v.y) << 16);
    }
    if (blockIdx.x < SC_BLOCKS) {
        __shared__ int lh[NB];
        for (int i = threadIdx.x; i < NB; i += 256) lh[i] = 0;
        __syncthreads();
        const int base4 = blockIdx.x * (SC_CHUNK / 4);
        #pragma unroll
        for (int j = 0; j < 4; ++j) {
            const int idx4 = base4 + threadIdx.x + j * 256;
            if (idx4 * 4 < N_EDGES) {           // N_EDGES % 4 == 0 -> full quad valid
                const int4 r4 = ((const int4*)ei)[idx4];
                atomicAdd(&lh[r4.x >> 8], 1);
                atomicAdd(&lh[r4.y >> 8], 1);
                atomicAdd(&lh[r4.z >> 8], 1);
                atomicAdd(&lh[r4.w >> 8], 1);
            }
        }
        __syncthreads();
        int* row = partial + (size_t)blockIdx.x * NB;
        for (int i = threadIdx.x; i < NB; i += 256) row[i] = lh[i];
    }
}

// ---------------- parallel column scan: per-(block,bucket) bases ----------
__global__ __launch_bounds__(256) void scan_cols(int* __restrict__ partial,
                                                 int* __restrict__ btot) {
    __shared__ int s[256];
    const int b = blockIdx.x;
    const int t = threadIdx.x;
    const int v = (t < SC_BLOCKS) ? partial[(size_t)t * NB + b] : 0;
    s[t] = v;
    __syncthreads();
    for (int d2 = 1; d2 < 256; d2 <<= 1) {
        int u = (t >= d2) ? s[t - d2] : 0;
        __syncthreads();
        s[t] += u;
        __syncthreads();
    }
    if (t < SC_BLOCKS) partial[(size_t)t * NB + b] = s[t] - v;
    if (t == 255) btot[b] = s[255];
}

// ---------------- single-pass scatter into bucket runs (int4 staged) -------
// pack: hi32 = col(16b) | r8<<16 ; lo32 = f32 weight bits
__global__ __launch_bounds__(SC_THREADS) void edge_scatter(const int* __restrict__ ei,
                                                           const float* __restrict__ ew,
                                                           const int* __restrict__ partial,
                                                           const int* __restrict__ btot,
                                                           ull* __restrict__ packed) {
    __shared__ int sb[256];
    __shared__ int lbase[NB];
    __shared__ int lcur[NB];
    const int t = threadIdx.x;
    const int bv = (t < NB) ? btot[t] : 0;
    sb[t] = bv;
    __syncthreads();
    for (int d2 = 1; d2 < 256; d2 <<= 1) {
        int u = (t >= d2) ? sb[t - d2] : 0;
        __syncthreads();
        sb[t] += u;
        __syncthreads();
    }
    const int* row = partial + (size_t)blockIdx.x * NB;
    if (t < NB) {
        lbase[t] = (sb[t] - bv) + row[t];   // boffs[t] + per-block base
        lcur[t]  = 0;
    }
    __syncthreads();

    // stage 16 edges as 4x int4/float4 (N_EDGES % 4 == 0 -> quad-granular guard)
    const int base4 = blockIdx.x * (SC_CHUNK / 4);
    int4   r4[4];
    int4   c4[4];
    float4 w4[4];
    #pragma unroll
    for (int j = 0; j < 4; ++j) {
        const int idx4 = base4 + t + j * 256;
        if (idx4 * 4 < N_EDGES) {
            r4[j] = ((const int4*)ei)[idx4];
            c4[j] = ((const int4*)(ei + N_EDGES))[idx4];
            w4[j] = ((const float4*)ew)[idx4];
        } else {
            r4[j] = make_int4(-1, -1, -1, -1);
            c4[j] = make_int4(0, 0, 0, 0);
            w4[j] = make_float4(0.f, 0.f, 0.f, 0.f);
        }
    }
    #pragma unroll
    for (int j = 0; j < 4; ++j) {
        const int   rr[4] = {r4[j].x, r4[j].y, r4[j].z, r4[j].w};
        const int   cc[4] = {c4[j].x, c4[j].y, c4[j].z, c4[j].w};
        const float ww[4] = {w4[j].x, w4[j].y, w4[j].z, w4[j].w};
        #pragma unroll
        for (int k = 0; k < 4; ++k) {
            const int r = rr[k];
            if (r >= 0) {
                const int bb   = r >> 8;
                const int lpos = atomicAdd(&lcur[bb], 1);
                const unsigned hi = (unsigned)cc[k] | ((unsigned)(r & 255) << 16);
                packed[lbase[bb] + lpos] = ((ull)hi << 32) | (ull)(unsigned)__float_as_uint(ww[k]);
            }
        }
    }
}

// ---------------- within-bucket node sort + CSR offsets + 4B compaction ----
__global__ __launch_bounds__(256) void node_sort(const int* __restrict__ btot,
                                                 int* __restrict__ offs,
                                                 const ull* __restrict__ packed,
                                                 unsigned* __restrict__ cedges) {
    __shared__ int cur[256];
    __shared__ int sc[256];
    __shared__ int sBase, sEnd;
    const int b = blockIdx.x;
    const int t = threadIdx.x;

    const int bv = (t < NB) ? btot[t] : 0;
    sc[t] = bv;
    __syncthreads();
    for (int d2 = 1; d2 < 256; d2 <<= 1) {
        int u = (t >= d2) ? sc[t - d2] : 0;
        __syncthreads();
        sc[t] += u;
        __syncthreads();
    }
    if (t == b) { sBase = sc[t] - bv; sEnd = sc[t]; }
    __syncthreads();
    const int s = sBase;
    const int e = sEnd;

    ull st[NS_EPT];
    #pragma unroll
    for (int i = 0; i < NS_EPT; ++i) {
        const int idx = s + t + i * 256;
        st[i] = (idx < e) ? packed[idx] : ~0ull;
    }
    cur[t] = 0;
    __syncthreads();
    #pragma unroll
    for (int i = 0; i < NS_EPT; ++i) {
        if (st[i] != ~0ull) atomicAdd(&cur[(int)((st[i] >> 48) & 0xff)], 1);
    }
    __syncthreads();
    const int v = cur[t];
    sc[t] = v;
    __syncthreads();
    for (int d2 = 1; d2 < 256; d2 <<= 1) {
        int u = (t >= d2) ? sc[t - d2] : 0;
        __syncthreads();
        sc[t] += u;
        __syncthreads();
    }
    const int excl = sc[t] - v;
    const int n = b * 256 + t;
    if (n < N_NODES) offs[n] = s + excl;
    if (b == 0 && t == 0) offs[N_NODES] = N_EDGES;
    cur[t] = excl;
    __syncthreads();
    #pragma unroll
    for (int i = 0; i < NS_EPT; ++i) {
        if (st[i] != ~0ull) {
            const int r8  = (int)((st[i] >> 48) & 0xff);
            const int pos = atomicAdd(&cur[r8], 1);
            const unsigned hi  = (unsigned)(st[i] >> 32);
            const unsigned col = hi & 0xffffu;
            const unsigned wbf = f2bf(__uint_as_float((unsigned)st[i]));
            cedges[s + pos] = (col << 16) | wbf;
        }
    }
}

// ---------------- half-wave-per-node aggregation (dwordx4 gathers) --------
__global__ __launch_bounds__(256) void sage_aggregate(const unsigned* __restrict__ xh,
                                                      const int* __restrict__ offs,
                                                      const unsigned* __restrict__ cedges,
                                                      unsigned* __restrict__ meanh) {
    const int n = (blockIdx.x * 256 + threadIdx.x) >> 5;   // half-wave id = node
    if (n >= N_NODES) return;
    const int l32 = threadIdx.x & 31;
    const int eg  = l32 >> 3;
    const int wq  = l32 & 7;
    const int s = offs[n];
    const int t = offs[n + 1];

    float ax0 = 0.f, ay0 = 0.f, ax1 = 0.f, ay1 = 0.f;
    float ax2 = 0.f, ay2 = 0.f, ax3 = 0.f, ay3 = 0.f;
    float bx0 = 0.f, by0 = 0.f, bx1 = 0.f, by1 = 0.f;
    float bx2 = 0.f, by2 = 0.f, bx3 = 0.f, by3 = 0.f;

    if (t > s) {
        const int tm1 = t - 1;
        for (int g = s; g < t; g += 8) {
            const int eA = g + eg;
            const int eB = g + 4 + eg;
            const unsigned cA = cedges[min(eA, tm1)];
            const unsigned cB = cedges[min(eB, tm1)];
            const float wA = (eA < t) ? bf2f(cA & 0xffffu) : 0.0f;
            const float wB = (eB < t) ? bf2f(cB & 0xffffu) : 0.0f;
            const uint4 vA = *(const uint4*)(xh + (size_t)(cA >> 16) * (D / 2) + wq * 4);
            const uint4 vB = *(const uint4*)(xh + (size_t)(cB >> 16) * (D / 2) + wq * 4);
            ax0 = fmaf(__uint_as_float(vA.x << 16),         wA, ax0);
            ay0 = fmaf(__uint_as_float(vA.x & 0xffff0000u), wA, ay0);
            ax1 = fmaf(__uint_as_float(vA.y << 16),         wA, ax1);
            ay1 = fmaf(__uint_as_float(vA.y & 0xffff0000u), wA, ay1);
            ax2 = fmaf(__uint_as_float(vA.z << 16),         wA, ax2);
            ay2 = fmaf(__uint_as_float(vA.z & 0xffff0000u), wA, ay2);
            ax3 = fmaf(__uint_as_float(vA.w << 16),         wA, ax3);
            ay3 = fmaf(__uint_as_float(vA.w & 0xffff0000u), wA, ay3);
            bx0 = fmaf(__uint_as_float(vB.x << 16),         wB, bx0);
            by0 = fmaf(__uint_as_float(vB.x & 0xffff0000u), wB, by0);
            bx1 = fmaf(__uint_as_float(vB.y << 16),         wB, bx1);
            by1 = fmaf(__uint_as_float(vB.y & 0xffff0000u), wB, by1);
            bx2 = fmaf(__uint_as_float(vB.z << 16),         wB, bx2);
            by2 = fmaf(__uint_as_float(vB.z & 0xffff0000u), wB, by2);
            bx3 = fmaf(__uint_as_float(vB.w << 16),         wB, bx3);
            by3 = fmaf(__uint_as_float(vB.w & 0xffff0000u), wB, by3);
        }
    }
    float sx0 = ax0 + bx0, sy0 = ay0 + by0;
    float sx1 = ax1 + bx1, sy1 = ay1 + by1;
    float sx2 = ax2 + bx2, sy2 = ay2 + by2;
    float sx3 = ax3 + bx3, sy3 = ay3 + by3;
    sx0 += __shfl_xor(sx0, 8);  sx0 += __shfl_xor(sx0, 16);
    sy0 += __shfl_xor(sy0, 8);  sy0 += __shfl_xor(sy0, 16);
    sx1 += __shfl_xor(sx1, 8);  sx1 += __shfl_xor(sx1, 16);
    sy1 += __shfl_xor(sy1, 8);  sy1 += __shfl_xor(sy1, 16);
    sx2 += __shfl_xor(sx2, 8);  sx2 += __shfl_xor(sx2, 16);
    sy2 += __shfl_xor(sy2, 8);  sy2 += __shfl_xor(sy2, 16);
    sx3 += __shfl_xor(sx3, 8);  sx3 += __shfl_xor(sx3, 16);
    sy3 += __shfl_xor(sy3, 8);  sy3 += __shfl_xor(sy3, 16);

    if (eg == 0) {
        const float inv = 1.0f / fmaxf((float)(t - s), 1.0f);
        uint4 r;
        r.x = f2bf(sx0 * inv) | (f2bf(sy0 * inv) << 16);
        r.y = f2bf(sx1 * inv) | (f2bf(sy1 * inv) << 16);
        r.z = f2bf(sx2 * inv) | (f2bf(sy2 * inv) << 16);
        r.w = f2bf(sx3 * inv) | (f2bf(sy3 * inv) << 16);
        *(uint4*)(meanh + (size_t)n * (D / 2) + wq * 4) = r;
    }
}

// ---------------- MFMA projection: 16-node x 128-output tile per wave -----
__global__ __launch_bounds__(256) void sage_project(const unsigned* __restrict__ xh,
                                                    const unsigned* __restrict__ meanh,
                                                    const float* __restrict__ skern,
                                                    const float* __restrict__ nkern,
                                                    const float* __restrict__ bias,
                                                    float* __restrict__ out) {
    const int lane = threadIdx.x & 63;
    const int wid  = (blockIdx.x * 256 + threadIdx.x) >> 6;
    const int r16  = lane & 15;
    const int g    = lane >> 4;

    bf16x8 bfrag[16];
    #pragma unroll
    for (int ct = 0; ct < 8; ++ct) {
        const float* K = (ct < 4) ? skern : nkern;
        const int col = (ct & 3) * 16 + r16;
        #pragma unroll
        for (int kh = 0; kh < 2; ++kh) {
            bf16x8 f;
            #pragma unroll
            for (int j = 0; j < 8; ++j) {
                const int k = kh * 32 + 8 * g + j;
                f[j] = (short)f2bf(K[k * 64 + col]);
            }
            bfrag[ct * 2 + kh] = f;
        }
    }

    if (wid >= NTILES) return;
    const int n0 = wid * 16;

    const unsigned* xrow = xh    + (size_t)(n0 + r16) * (D / 2);
    const unsigned* mrow = meanh + (size_t)(n0 + r16) * (D / 2);
    const bf16x8 aS0 = *(const bf16x8*)(xrow + 4 * g);
    const bf16x8 aS1 = *(const bf16x8*)(xrow + 16 + 4 * g);
    const bf16x8 aN0 = *(const bf16x8*)(mrow + 4 * g);
    const bf16x8 aN1 = *(const bf16x8*)(mrow + 16 + 4 * g);

    f32x4 acc[8];
    #pragma unroll
    for (int ct = 0; ct < 8; ++ct) {
        f32x4 c = {0.f, 0.f, 0.f, 0.f};
        c = __builtin_amdgcn_mfma_f32_16x16x32_bf16(ct < 4 ? aS0 : aN0, bfrag[ct * 2 + 0], c, 0, 0, 0);
        c = __builtin_amdgcn_mfma_f32_16x16x32_bf16(ct < 4 ? aS1 : aN1, bfrag[ct * 2 + 1], c, 0, 0, 0);
        acc[ct] = c;
    }

    #pragma unroll
    for (int ct = 0; ct < 8; ++ct) {
        const int col = (ct < 4 ? 0 : 64) + (ct & 3) * 16 + r16;
        const float bj = bias[col];
        #pragma unroll
        for (int r = 0; r < 4; ++r) {
            const int node = n0 + 4 * g + r;
            out[(size_t)node * UNITS + col] = fmaxf(acc[ct][r] + bj, 0.0f);
        }
    }
}

extern "C" void kernel_launch(void* const* d_in, const int* in_sizes, int n_in,
                              void* d_out, int out_size, void* d_ws, size_t ws_size,
                              hipStream_t stream) {
    const float* x     = (const float*)d_in[0];
    const int*   ei    = (const int*)  d_in[1];
    const float* ew    = (const float*)d_in[2];
    const float* skern = (const float*)d_in[3];
    const float* nkern = (const float*)d_in[4];
    const float* bias  = (const float*)d_in[5];
    float* out = (float*)d_out;

    auto align256 = [](size_t v) { return (v + 255) & ~size_t(255); };
    const size_t szM  = align256((size_t)SC_BLOCKS * NB * sizeof(int));   // partials matrix
    const size_t szT  = align256((size_t)NB * sizeof(int));               // bucket totals
    const size_t szNO = align256((size_t)(N_NODES + 1) * sizeof(int));
    const size_t szP  = align256((size_t)N_EDGES * sizeof(ull));
    const size_t szC  = align256((size_t)N_EDGES * sizeof(unsigned));
    const size_t szX  = align256((size_t)N_NODES * (D / 2) * sizeof(unsigned));

    char* w = (char*)d_ws;
    int*      partial = (int*)w;
    int*      btot    = (int*)(w + szM);
    int*      offs    = (int*)(w + szM + szT);
    ull*      packed  = (ull*)(w + szM + szT + szNO);
    unsigned* cedges  = (unsigned*)(w + szM + szT + szNO + szP);
    unsigned* xh      = (unsigned*)(w + szM + szT + szNO + szP + szC);
    unsigned* meanh   = (unsigned*)(w + szM + szT + szNO + szP + szC + szX);
    (void)ws_size; (void)in_sizes; (void)n_in; (void)out_size;

    prep          <<<PREP_BLOCKS, 256, 0, stream>>>(x, xh, ei, partial);
    scan_cols     <<<NB, 256, 0, stream>>>(partial, btot);
    edge_scatter  <<<SC_BLOCKS, SC_THREADS, 0, stream>>>(ei, ew, partial, btot, packed);
    node_sort     <<<NB, SC_THREADS, 0, stream>>>(btot, offs, packed, cedges);
    sage_aggregate<<<(N_NODES * 32 + 255) / 256, 256, 0, stream>>>(xh, offs, cedges, meanh);
    sage_project  <<<PJ_BLOCKS, 256, 0, stream>>>(xh, meanh, skern, nkern, bias, out);
}

// Round 18
// 60.428 us; speedup vs baseline: 3.1741x; 1.0015x over previous
//
#include <hip/hip_runtime.h>

// MeanGraphSage: h = relu(concat(x @ Ws, mean_neighbors @ Wn) + bias)
// N=50000 nodes, E=800000 edges, D=64 in-feats, 128 out (64+64 concat).
//
// Round 18 (from 60.5us r17): fuse aggregate+projection WITHOUT r9's serial
// trap. Block = 512 threads: 16 half-waves aggregate 16 nodes (geometry
// identical to r17), means land in LDS meanl[16][36]; one barrier; then the
// 8 waves each compute one 16-col MFMA tile of the same 16-node output
// (wave<4: self half from xh; wave>=4: neighbor half from LDS). Kills the
// meanh round-trip (12.8MB) and one launch. Rest identical to r17.

typedef unsigned long long ull;
typedef __attribute__((ext_vector_type(8))) short bf16x8;
typedef __attribute__((ext_vector_type(4))) float f32x4;

constexpr int N_NODES = 50000;
constexpr int N_EDGES = 800000;
constexpr int D = 64;
constexpr int UNITS = 128;
constexpr int NB = (N_NODES + 255) / 256;           // 196 buckets of 256 nodes
constexpr int SC_EPT = 16;                           // edges/thread
constexpr int SC_THREADS = 256;
constexpr int SC_CHUNK = SC_EPT * SC_THREADS;        // 4096
constexpr int SC_BLOCKS = (N_EDGES + SC_CHUNK - 1) / SC_CHUNK;  // 196
constexpr int NS_EPT = 24;                           // bucket capacity 6144
constexpr int PREP_BLOCKS = 2048;
constexpr int AP_BLOCKS = N_NODES / 16;              // 3125 (exact)

__device__ __forceinline__ unsigned f2bf(float f) {   // RNE f32 -> bf16 bits
    unsigned u = __float_as_uint(f);
    return (u + 0x7fffu + ((u >> 16) & 1u)) >> 16;
}
__device__ __forceinline__ float bf2f(unsigned b) {
    return __uint_as_float(b << 16);
}

// ---------------- prep: x->bf16 table + bucket histogram (int4 loads) -------
__global__ __launch_bounds__(256) void prep(const float* __restrict__ x,
                                            unsigned* __restrict__ xh,
                                            const int* __restrict__ ei,
                                            int* __restrict__ partial) {
    constexpr int XW = N_NODES * (D / 2);   // 1.6M packed words
    for (int i = blockIdx.x * 256 + threadIdx.x; i < XW; i += PREP_BLOCKS * 256) {
        const float2 v = ((const float2*)x)[i];
        xh[i] = f2bf(v.x) | (f2bf(v.y) << 16);
    }
    if (blockIdx.x < SC_BLOCKS) {
        __shared__ int lh[NB];
        for (int i = threadIdx.x; i < NB; i += 256) lh[i] = 0;
        __syncthreads();
        const int base4 = blockIdx.x * (SC_CHUNK / 4);
        #pragma unroll
        for (int j = 0; j < 4; ++j) {
            const int idx4 = base4 + threadIdx.x + j * 256;
            if (idx4 * 4 < N_EDGES) {           // N_EDGES % 4 == 0 -> full quad valid
                const int4 r4 = ((const int4*)ei)[idx4];
                atomicAdd(&lh[r4.x >> 8], 1);
                atomicAdd(&lh[r4.y >> 8], 1);
                atomicAdd(&lh[r4.z >> 8], 1);
                atomicAdd(&lh[r4.w >> 8], 1);
            }
        }
        __syncthreads();
        int* row = partial + (size_t)blockIdx.x * NB;
        for (int i = threadIdx.x; i < NB; i += 256) row[i] = lh[i];
    }
}

// ---------------- parallel column scan: per-(block,bucket) bases ----------
__global__ __launch_bounds__(256) void scan_cols(int* __restrict__ partial,
                                                 int* __restrict__ btot) {
    __shared__ int s[256];
    const int b = blockIdx.x;
    const int t = threadIdx.x;
    const int v = (t < SC_BLOCKS) ? partial[(size_t)t * NB + b] : 0;
    s[t] = v;
    __syncthreads();
    for (int d2 = 1; d2 < 256; d2 <<= 1) {
        int u = (t >= d2) ? s[t - d2] : 0;
        __syncthreads();
        s[t] += u;
        __syncthreads();
    }
    if (t < SC_BLOCKS) partial[(size_t)t * NB + b] = s[t] - v;
    if (t == 255) btot[b] = s[255];
}

// ---------------- single-pass scatter into bucket runs (int4 staged) -------
// pack: hi32 = col(16b) | r8<<16 ; lo32 = f32 weight bits
__global__ __launch_bounds__(SC_THREADS) void edge_scatter(const int* __restrict__ ei,
                                                           const float* __restrict__ ew,
                                                           const int* __restrict__ partial,
                                                           const int* __restrict__ btot,
                                                           ull* __restrict__ packed) {
    __shared__ int sb[256];
    __shared__ int lbase[NB];
    __shared__ int lcur[NB];
    const int t = threadIdx.x;
    const int bv = (t < NB) ? btot[t] : 0;
    sb[t] = bv;
    __syncthreads();
    for (int d2 = 1; d2 < 256; d2 <<= 1) {
        int u = (t >= d2) ? sb[t - d2] : 0;
        __syncthreads();
        sb[t] += u;
        __syncthreads();
    }
    const int* row = partial + (size_t)blockIdx.x * NB;
    if (t < NB) {
        lbase[t] = (sb[t] - bv) + row[t];   // boffs[t] + per-block base
        lcur[t]  = 0;
    }
    __syncthreads();

    const int base4 = blockIdx.x * (SC_CHUNK / 4);
    int4   r4[4];
    int4   c4[4];
    float4 w4[4];
    #pragma unroll
    for (int j = 0; j < 4; ++j) {
        const int idx4 = base4 + t + j * 256;
        if (idx4 * 4 < N_EDGES) {
            r4[j] = ((const int4*)ei)[idx4];
            c4[j] = ((const int4*)(ei + N_EDGES))[idx4];
            w4[j] = ((const float4*)ew)[idx4];
        } else {
            r4[j] = make_int4(-1, -1, -1, -1);
            c4[j] = make_int4(0, 0, 0, 0);
            w4[j] = make_float4(0.f, 0.f, 0.f, 0.f);
        }
    }
    #pragma unroll
    for (int j = 0; j < 4; ++j) {
        const int   rr[4] = {r4[j].x, r4[j].y, r4[j].z, r4[j].w};
        const int   cc[4] = {c4[j].x, c4[j].y, c4[j].z, c4[j].w};
        const float ww[4] = {w4[j].x, w4[j].y, w4[j].z, w4[j].w};
        #pragma unroll
        for (int k = 0; k < 4; ++k) {
            const int r = rr[k];
            if (r >= 0) {
                const int bb   = r >> 8;
                const int lpos = atomicAdd(&lcur[bb], 1);
                const unsigned hi = (unsigned)cc[k] | ((unsigned)(r & 255) << 16);
                packed[lbase[bb] + lpos] = ((ull)hi << 32) | (ull)(unsigned)__float_as_uint(ww[k]);
            }
        }
    }
}

// ---------------- within-bucket node sort + CSR offsets + 4B compaction ----
__global__ __launch_bounds__(256) void node_sort(const int* __restrict__ btot,
                                                 int* __restrict__ offs,
                                                 const ull* __restrict__ packed,
                                                 unsigned* __restrict__ cedges) {
    __shared__ int cur[256];
    __shared__ int sc[256];
    __shared__ int sBase, sEnd;
    const int b = blockIdx.x;
    const int t = threadIdx.x;

    const int bv = (t < NB) ? btot[t] : 0;
    sc[t] = bv;
    __syncthreads();
    for (int d2 = 1; d2 < 256; d2 <<= 1) {
        int u = (t >= d2) ? sc[t - d2] : 0;
        __syncthreads();
        sc[t] += u;
        __syncthreads();
    }
    if (t == b) { sBase = sc[t] - bv; sEnd = sc[t]; }
    __syncthreads();
    const int s = sBase;
    const int e = sEnd;

    ull st[NS_EPT];
    #pragma unroll
    for (int i = 0; i < NS_EPT; ++i) {
        const int idx = s + t + i * 256;
        st[i] = (idx < e) ? packed[idx] : ~0ull;
    }
    cur[t] = 0;
    __syncthreads();
    #pragma unroll
    for (int i = 0; i < NS_EPT; ++i) {
        if (st[i] != ~0ull) atomicAdd(&cur[(int)((st[i] >> 48) & 0xff)], 1);
    }
    __syncthreads();
    const int v = cur[t];
    sc[t] = v;
    __syncthreads();
    for (int d2 = 1; d2 < 256; d2 <<= 1) {
        int u = (t >= d2) ? sc[t - d2] : 0;
        __syncthreads();
        sc[t] += u;
        __syncthreads();
    }
    const int excl = sc[t] - v;
    const int n = b * 256 + t;
    if (n < N_NODES) offs[n] = s + excl;
    if (b == 0 && t == 0) offs[N_NODES] = N_EDGES;
    cur[t] = excl;
    __syncthreads();
    #pragma unroll
    for (int i = 0; i < NS_EPT; ++i) {
        if (st[i] != ~0ull) {
            const int r8  = (int)((st[i] >> 48) & 0xff);
            const int pos = atomicAdd(&cur[r8], 1);
            const unsigned hi  = (unsigned)(st[i] >> 32);
            const unsigned col = hi & 0xffffu;
            const unsigned wbf = f2bf(__uint_as_float((unsigned)st[i]));
            cedges[s + pos] = (col << 16) | wbf;
        }
    }
}

// ---------------- fused aggregate + MFMA projection ----------------
// Block = 512 threads. Phase 1: 16 half-waves aggregate 16 nodes (r17
// geometry: dwordx4 gathers, shfl_xor reduce) -> LDS meanl[16][36].
// Phase 2: wave w (0..7) computes col-tile w of the 16-node x 128 output:
// w<4 self (A from xh), w>=4 neighbor (A from LDS). One barrier total.
__global__ __launch_bounds__(512) void sage_agg_proj(const unsigned* __restrict__ xh,
                                                     const int* __restrict__ offs,
                                                     const unsigned* __restrict__ cedges,
                                                     const float* __restrict__ skern,
                                                     const float* __restrict__ nkern,
                                                     const float* __restrict__ bias,
                                                     float* __restrict__ out) {
    __shared__ unsigned meanl[16][36];   // rows padded: 16B-aligned b128 reads
    const int tid = threadIdx.x;
    const int n0  = blockIdx.x * 16;

    // ---- phase 1: half-wave hw aggregates node n0+hw
    {
        const int hw  = tid >> 5;
        const int l32 = tid & 31;
        const int eg  = l32 >> 3;
        const int wq  = l32 & 7;
        const int n = n0 + hw;
        const int s = offs[n];
        const int t = offs[n + 1];

        float ax0 = 0.f, ay0 = 0.f, ax1 = 0.f, ay1 = 0.f;
        float ax2 = 0.f, ay2 = 0.f, ax3 = 0.f, ay3 = 0.f;
        float bx0 = 0.f, by0 = 0.f, bx1 = 0.f, by1 = 0.f;
        float bx2 = 0.f, by2 = 0.f, bx3 = 0.f, by3 = 0.f;

        if (t > s) {
            const int tm1 = t - 1;
            for (int g = s; g < t; g += 8) {
                const int eA = g + eg;
                const int eB = g + 4 + eg;
                const unsigned cA = cedges[min(eA, tm1)];
                const unsigned cB = cedges[min(eB, tm1)];
                const float wA = (eA < t) ? bf2f(cA & 0xffffu) : 0.0f;
                const float wB = (eB < t) ? bf2f(cB & 0xffffu) : 0.0f;
                const uint4 vA = *(const uint4*)(xh + (size_t)(cA >> 16) * (D / 2) + wq * 4);
                const uint4 vB = *(const uint4*)(xh + (size_t)(cB >> 16) * (D / 2) + wq * 4);
                ax0 = fmaf(__uint_as_float(vA.x << 16),         wA, ax0);
                ay0 = fmaf(__uint_as_float(vA.x & 0xffff0000u), wA, ay0);
                ax1 = fmaf(__uint_as_float(vA.y << 16),         wA, ax1);
                ay1 = fmaf(__uint_as_float(vA.y & 0xffff0000u), wA, ay1);
                ax2 = fmaf(__uint_as_float(vA.z << 16),         wA, ax2);
                ay2 = fmaf(__uint_as_float(vA.z & 0xffff0000u), wA, ay2);
                ax3 = fmaf(__uint_as_float(vA.w << 16),         wA, ax3);
                ay3 = fmaf(__uint_as_float(vA.w & 0xffff0000u), wA, ay3);
                bx0 = fmaf(__uint_as_float(vB.x << 16),         wB, bx0);
                by0 = fmaf(__uint_as_float(vB.x & 0xffff0000u), wB, by0);
                bx1 = fmaf(__uint_as_float(vB.y << 16),         wB, bx1);
                by1 = fmaf(__uint_as_float(vB.y & 0xffff0000u), wB, by1);
                bx2 = fmaf(__uint_as_float(vB.z << 16),         wB, bx2);
                by2 = fmaf(__uint_as_float(vB.z & 0xffff0000u), wB, by2);
                bx3 = fmaf(__uint_as_float(vB.w << 16),         wB, bx3);
                by3 = fmaf(__uint_as_float(vB.w & 0xffff0000u), wB, by3);
            }
        }
        float sx0 = ax0 + bx0, sy0 = ay0 + by0;
        float sx1 = ax1 + bx1, sy1 = ay1 + by1;
        float sx2 = ax2 + bx2, sy2 = ay2 + by2;
        float sx3 = ax3 + bx3, sy3 = ay3 + by3;
        sx0 += __shfl_xor(sx0, 8);  sx0 += __shfl_xor(sx0, 16);
        sy0 += __shfl_xor(sy0, 8);  sy0 += __shfl_xor(sy0, 16);
        sx1 += __shfl_xor(sx1, 8);  sx1 += __shfl_xor(sx1, 16);
        sy1 += __shfl_xor(sy1, 8);  sy1 += __shfl_xor(sy1, 16);
        sx2 += __shfl_xor(sx2, 8);  sx2 += __shfl_xor(sx2, 16);
        sy2 += __shfl_xor(sy2, 8);  sy2 += __shfl_xor(sy2, 16);
        sx3 += __shfl_xor(sx3, 8);  sx3 += __shfl_xor(sx3, 16);
        sy3 += __shfl_xor(sy3, 8);  sy3 += __shfl_xor(sy3, 16);

        if (eg == 0) {
            const float inv = 1.0f / fmaxf((float)(t - s), 1.0f);
            uint4 r;
            r.x = f2bf(sx0 * inv) | (f2bf(sy0 * inv) << 16);
            r.y = f2bf(sx1 * inv) | (f2bf(sy1 * inv) << 16);
            r.z = f2bf(sx2 * inv) | (f2bf(sy2 * inv) << 16);
            r.w = f2bf(sx3 * inv) | (f2bf(sy3 * inv) << 16);
            *(uint4*)&meanl[hw][wq * 4] = r;
        }
    }
    __syncthreads();

    // ---- phase 2: wave w computes its 16-col tile of the 16-node output
    {
        const int w    = tid >> 6;        // 0..7
        const int lane = tid & 63;
        const int r16  = lane & 15;
        const int g    = lane >> 4;
        const float* K = (w < 4) ? skern : nkern;
        const int col  = (w & 3) * 16 + r16;

        bf16x8 b0, b1;
        #pragma unroll
        for (int j = 0; j < 8; ++j) {
            b0[j] = (short)f2bf(K[(8 * g + j) * 64 + col]);
            b1[j] = (short)f2bf(K[(32 + 8 * g + j) * 64 + col]);
        }

        bf16x8 a0, a1;
        if (w < 4) {
            const unsigned* xrow = xh + (size_t)(n0 + r16) * (D / 2);
            a0 = *(const bf16x8*)(xrow + 4 * g);
            a1 = *(const bf16x8*)(xrow + 16 + 4 * g);
        } else {
            a0 = *(const bf16x8*)&meanl[r16][4 * g];
            a1 = *(const bf16x8*)&meanl[r16][16 + 4 * g];
        }

        f32x4 c = {0.f, 0.f, 0.f, 0.f};
        c = __builtin_amdgcn_mfma_f32_16x16x32_bf16(a0, b0, c, 0, 0, 0);
        c = __builtin_amdgcn_mfma_f32_16x16x32_bf16(a1, b1, c, 0, 0, 0);

        const int ocol = (w < 4 ? 0 : 64) + (w & 3) * 16 + r16;
        const float bj = bias[ocol];
        #pragma unroll
        for (int r = 0; r < 4; ++r) {
            out[(size_t)(n0 + 4 * g + r) * UNITS + ocol] = fmaxf(c[r] + bj, 0.0f);
        }
    }
}

extern "C" void kernel_launch(void* const* d_in, const int* in_sizes, int n_in,
                              void* d_out, int out_size, void* d_ws, size_t ws_size,
                              hipStream_t stream) {
    const float* x     = (const float*)d_in[0];
    const int*   ei    = (const int*)  d_in[1];
    const float* ew    = (const float*)d_in[2];
    const float* skern = (const float*)d_in[3];
    const float* nkern = (const float*)d_in[4];
    const float* bias  = (const float*)d_in[5];
    float* out = (float*)d_out;

    auto align256 = [](size_t v) { return (v + 255) & ~size_t(255); };
    const size_t szM  = align256((size_t)SC_BLOCKS * NB * sizeof(int));   // partials matrix
    const size_t szT  = align256((size_t)NB * sizeof(int));               // bucket totals
    const size_t szNO = align256((size_t)(N_NODES + 1) * sizeof(int));
    const size_t szP  = align256((size_t)N_EDGES * sizeof(ull));
    const size_t szC  = align256((size_t)N_EDGES * sizeof(unsigned));

    char* w = (char*)d_ws;
    int*      partial = (int*)w;
    int*      btot    = (int*)(w + szM);
    int*      offs    = (int*)(w + szM + szT);
    ull*      packed  = (ull*)(w + szM + szT + szNO);
    unsigned* cedges  = (unsigned*)(w + szM + szT + szNO + szP);
    unsigned* xh      = (unsigned*)(w + szM + szT + szNO + szP + szC);
    (void)ws_size; (void)in_sizes; (void)n_in; (void)out_size;

    prep         <<<PREP_BLOCKS, 256, 0, stream>>>(x, xh, ei, partial);
    scan_cols    <<<NB, 256, 0, stream>>>(partial, btot);
    edge_scatter <<<SC_BLOCKS, SC_THREADS, 0, stream>>>(ei, ew, partial, btot, packed);
    node_sort    <<<NB, SC_THREADS, 0, stream>>>(btot, offs, packed, cedges);
    sage_agg_proj<<<AP_BLOCKS, 512, 0, stream>>>(xh, offs, cedges, skern, nkern, bias, out);
}